// Round 1
// baseline (1992.031 us; speedup 1.0000x reference)
//
#include <hip/hip_runtime.h>
#include <cstdint>
#include <cmath>

#define BB 256
#define DD 128
#define RR 2304
#define QQ 65536
#define WW (BB + QQ)                    // 65792
#define SCORE_SZ ((size_t)BB * WW)      // 16842752
#define TOPK 5

// ---------- Kernel A: row-normalize q and k ----------
__global__ __launch_bounds__(64) void norm_rows_kernel(
    const float* __restrict__ q, const float* __restrict__ k,
    float* __restrict__ qn, float* __restrict__ kn) {
  int b = blockIdx.x;  // 0..511
  const float* src;
  float* dst;
  if (b < BB) { src = q + (size_t)b * DD; dst = qn + (size_t)b * DD; }
  else        { src = k + (size_t)(b - BB) * DD; dst = kn + (size_t)(b - BB) * DD; }
  int t = threadIdx.x;  // 0..63
  float x0 = src[t], x1 = src[t + 64];
  float s = x0 * x0 + x1 * x1;
  #pragma unroll
  for (int o = 32; o > 0; o >>= 1) s += __shfl_down(s, o);
  s = __shfl(s, 0);
  float rn = 1.0f / sqrtf(s);
  dst[t] = x0 * rn;
  dst[t + 64] = x1 * rn;
}

// ---------- Kernel B: score_batch = qn @ kn^T, mask_batch ----------
__global__ __launch_bounds__(256) void batch_kernel(
    const float* __restrict__ qn, const float* __restrict__ kn,
    const int* __restrict__ indices, float* __restrict__ out) {
  int i = blockIdx.x;
  int j = threadIdx.x;
  __shared__ float qs[DD];
  if (j < DD) qs[j] = qn[(size_t)i * DD + j];
  __syncthreads();
  const float* kr = kn + (size_t)j * DD;
  float acc = 0.f;
  #pragma unroll 8
  for (int d = 0; d < DD; d++) acc = fmaf(qs[d], kr[d], acc);
  out[(size_t)i * WW + j] = acc;
  out[SCORE_SZ + (size_t)i * WW + j] = (indices[i] == indices[j]) ? 1.0f : 0.0f;
}

// ---------- Kernel C1: score_ref = ref_feats @ ref_queue ----------
// Writes raw score_ref into the MASK region of out (scratch; overwritten later).
// Block: 256 threads -> 256 rows x 64 cols tile; thread tile 8x8.
__global__ __launch_bounds__(256) void gemm_ref_kernel(
    const float* __restrict__ A,   // [256, 2304]
    const float* __restrict__ Bm,  // [2304, 65536]
    float* __restrict__ out) {
  __shared__ __align__(16) float aT[16][256];
  __shared__ __align__(16) float bT[16][64];
  int tid = threadIdx.x;
  int tx = tid & 7;        // col group 0..7
  int ty = tid >> 3;       // row group 0..31
  int cbase = blockIdx.x * 64;
  float acc[8][8] = {};

  for (int r0 = 0; r0 < RR; r0 += 16) {
    __syncthreads();
    {  // A chunk: thread = row, 16 consecutive k as 4x float4
      const float4* src4 = (const float4*)(A + (size_t)tid * RR + r0);
      #pragma unroll
      for (int g = 0; g < 4; g++) {
        float4 v = src4[g];
        aT[4 * g + 0][tid] = v.x;
        aT[4 * g + 1][tid] = v.y;
        aT[4 * g + 2][tid] = v.z;
        aT[4 * g + 3][tid] = v.w;
      }
    }
    {  // B chunk: 4 (k,col) elements per thread, coalesced along cols
      int col = tid & 63, kk = tid >> 6;  // kk 0..3
      #pragma unroll
      for (int i = 0; i < 4; i++)
        bT[kk + 4 * i][col] = Bm[(size_t)(r0 + kk + 4 * i) * QQ + cbase + col];
    }
    __syncthreads();
    #pragma unroll 4
    for (int kk = 0; kk < 16; kk++) {
      float av[8], bv[8];
      *(float4*)(&av[0]) = *(const float4*)(&aT[kk][ty * 8]);
      *(float4*)(&av[4]) = *(const float4*)(&aT[kk][ty * 8 + 4]);
      *(float4*)(&bv[0]) = *(const float4*)(&bT[kk][tx * 8]);
      *(float4*)(&bv[4]) = *(const float4*)(&bT[kk][tx * 8 + 4]);
      #pragma unroll
      for (int i = 0; i < 8; i++)
        #pragma unroll
        for (int j = 0; j < 8; j++)
          acc[i][j] = fmaf(av[i], bv[j], acc[i][j]);
    }
  }
  float* dst = out + SCORE_SZ;  // mask region used as score_ref scratch
  #pragma unroll
  for (int i = 0; i < 8; i++) {
    int row = ty * 8 + i;
    float* p = dst + (size_t)row * WW + BB + cbase + tx * 8;
    float4 w0 = {acc[i][0], acc[i][1], acc[i][2], acc[i][3]};
    float4 w1 = {acc[i][4], acc[i][5], acc[i][6], acc[i][7]};
    *(float4*)p = w0;
    *(float4*)(p + 4) = w1;
  }
}

// ---------- Kernel C2: score_queue = qn @ moco; write -score_queue*score_ref ----------
__global__ __launch_bounds__(256) void gemm_moco_kernel(
    const float* __restrict__ A,   // qn [256, 128]
    const float* __restrict__ Bm,  // moco [128, 65536]
    float* __restrict__ out) {
  __shared__ __align__(16) float aT[16][256];
  __shared__ __align__(16) float bT[16][64];
  int tid = threadIdx.x;
  int tx = tid & 7;
  int ty = tid >> 3;
  int cbase = blockIdx.x * 64;
  float acc[8][8] = {};

  for (int r0 = 0; r0 < DD; r0 += 16) {
    __syncthreads();
    {
      const float4* src4 = (const float4*)(A + (size_t)tid * DD + r0);
      #pragma unroll
      for (int g = 0; g < 4; g++) {
        float4 v = src4[g];
        aT[4 * g + 0][tid] = v.x;
        aT[4 * g + 1][tid] = v.y;
        aT[4 * g + 2][tid] = v.z;
        aT[4 * g + 3][tid] = v.w;
      }
    }
    {
      int col = tid & 63, kk = tid >> 6;
      #pragma unroll
      for (int i = 0; i < 4; i++)
        bT[kk + 4 * i][col] = Bm[(size_t)(r0 + kk + 4 * i) * QQ + cbase + col];
    }
    __syncthreads();
    #pragma unroll 4
    for (int kk = 0; kk < 16; kk++) {
      float av[8], bv[8];
      *(float4*)(&av[0]) = *(const float4*)(&aT[kk][ty * 8]);
      *(float4*)(&av[4]) = *(const float4*)(&aT[kk][ty * 8 + 4]);
      *(float4*)(&bv[0]) = *(const float4*)(&bT[kk][tx * 8]);
      *(float4*)(&bv[4]) = *(const float4*)(&bT[kk][tx * 8 + 4]);
      #pragma unroll
      for (int i = 0; i < 8; i++)
        #pragma unroll
        for (int j = 0; j < 8; j++)
          acc[i][j] = fmaf(av[i], bv[j], acc[i][j]);
    }
  }
  const float* sref = out + SCORE_SZ;  // raw score_ref from C1
  #pragma unroll
  for (int i = 0; i < 8; i++) {
    int row = ty * 8 + i;
    size_t off = (size_t)row * WW + BB + cbase + tx * 8;
    float4 s0 = *(const float4*)(sref + off);
    float4 s1 = *(const float4*)(sref + off + 4);
    float4 w0 = {-acc[i][0] * s0.x, -acc[i][1] * s0.y, -acc[i][2] * s0.z, -acc[i][3] * s0.w};
    float4 w1 = {-acc[i][4] * s1.x, -acc[i][5] * s1.y, -acc[i][6] * s1.z, -acc[i][7] * s1.w};
    *(float4*)(out + off) = w0;
    *(float4*)(out + off + 4) = w1;
  }
}

// ---------- Kernel T: per-row top-5 of masked score_ref ----------
__global__ __launch_bounds__(256) void topk_kernel(
    const float* __restrict__ out, const int* __restrict__ indices,
    const int* __restrict__ index_queue, int* __restrict__ topk_out) {
  int row = blockIdx.x;
  int t = threadIdx.x;
  int myi = indices[row];
  const float* s = out + SCORE_SZ + (size_t)row * WW + BB;
  float tv[TOPK];
  int ti[TOPK];
  #pragma unroll
  for (int i = 0; i < TOPK; i++) { tv[i] = -INFINITY; ti[i] = 0x7fffffff; }
  for (int it = 0; it < QQ / 256; it++) {
    int j = (it << 8) + t;  // ascending per thread -> ties keep smaller j
    float val = (index_queue[j] == myi) ? -INFINITY : s[j];
    if (val > tv[TOPK - 1]) {
      tv[TOPK - 1] = val; ti[TOPK - 1] = j;
      #pragma unroll
      for (int u = TOPK - 2; u >= 0; u--) {
        if (tv[u + 1] > tv[u]) {
          float fv = tv[u]; tv[u] = tv[u + 1]; tv[u + 1] = fv;
          int fi = ti[u]; ti[u] = ti[u + 1]; ti[u + 1] = fi;
        }
      }
    }
  }
  __shared__ float cv[256 * TOPK];
  __shared__ int ci[256 * TOPK];
  #pragma unroll
  for (int i = 0; i < TOPK; i++) { cv[t * TOPK + i] = tv[i]; ci[t * TOPK + i] = ti[i]; }
  __syncthreads();
  if (t == 0) {
    float bv[TOPK];
    int bi[TOPK];
    #pragma unroll
    for (int i = 0; i < TOPK; i++) { bv[i] = -INFINITY; bi[i] = 0x7fffffff; }
    for (int c = 0; c < 256 * TOPK; c++) {
      float val = cv[c]; int idx = ci[c];
      // total order: value desc, index asc (lax.top_k tie-break)
      if (val > bv[TOPK - 1] || (val == bv[TOPK - 1] && idx < bi[TOPK - 1])) {
        bv[TOPK - 1] = val; bi[TOPK - 1] = idx;
        #pragma unroll
        for (int u = TOPK - 2; u >= 0; u--) {
          bool sw = (bv[u + 1] > bv[u]) || (bv[u + 1] == bv[u] && bi[u + 1] < bi[u]);
          if (sw) {
            float fv = bv[u]; bv[u] = bv[u + 1]; bv[u + 1] = fv;
            int fi = bi[u]; bi[u] = bi[u + 1]; bi[u + 1] = fi;
          }
        }
      }
    }
    #pragma unroll
    for (int i = 0; i < TOPK; i++) topk_out[row * TOPK + i] = bi[i];
  }
}

// ---------- Kernel M: overwrite mask region with base index-match mask ----------
__global__ __launch_bounds__(256) void mask_fill_kernel(
    const int* __restrict__ indices, const int* __restrict__ index_queue,
    float* __restrict__ out) {
  int row = blockIdx.x >> 8;
  int j = ((blockIdx.x & 255) << 8) + threadIdx.x;
  out[SCORE_SZ + (size_t)row * WW + BB + j] =
      (indices[row] == index_queue[j]) ? 1.0f : 0.0f;
}

// ---------- Kernel F: topk fixups (weighted_mask=+1, mask=1) ----------
__global__ __launch_bounds__(64) void fixup_kernel(
    const int* __restrict__ topk_idx, float* __restrict__ out) {
  int t = blockIdx.x * 64 + threadIdx.x;
  if (t >= BB * TOPK) return;
  int row = t / TOPK;
  int j = topk_idx[t];
  size_t o = (size_t)row * WW + BB + j;
  out[o] = -out[o];            // flip weighted_mask -1 -> +1
  out[SCORE_SZ + o] = 1.0f;    // mask set(1)
}

extern "C" void kernel_launch(void* const* d_in, const int* in_sizes, int n_in,
                              void* d_out, int out_size, void* d_ws, size_t ws_size,
                              hipStream_t stream) {
  (void)in_sizes; (void)n_in; (void)out_size; (void)ws_size;
  const float* q = (const float*)d_in[0];
  const float* k = (const float*)d_in[1];
  const float* ref_feats = (const float*)d_in[2];
  const float* moco_queue = (const float*)d_in[3];
  const float* ref_queue = (const float*)d_in[4];
  const int* indices = (const int*)d_in[5];
  const int* index_queue = (const int*)d_in[6];
  float* out = (float*)d_out;

  float* qn = (float*)d_ws;
  float* kn = qn + BB * DD;
  int* topk_idx = (int*)(kn + BB * DD);

  hipLaunchKernelGGL(norm_rows_kernel, dim3(2 * BB), dim3(64), 0, stream, q, k, qn, kn);
  hipLaunchKernelGGL(batch_kernel, dim3(BB), dim3(256), 0, stream, qn, kn, indices, out);
  hipLaunchKernelGGL(gemm_ref_kernel, dim3(QQ / 64), dim3(256), 0, stream, ref_feats, ref_queue, out);
  hipLaunchKernelGGL(gemm_moco_kernel, dim3(QQ / 64), dim3(256), 0, stream, qn, moco_queue, out);
  hipLaunchKernelGGL(topk_kernel, dim3(BB), dim3(256), 0, stream, out, indices, index_queue, topk_idx);
  hipLaunchKernelGGL(mask_fill_kernel, dim3(BB * 256), dim3(256), 0, stream, indices, index_queue, out);
  hipLaunchKernelGGL(fixup_kernel, dim3(20), dim3(64), 0, stream, topk_idx, out);
}

// Round 2
// 1374.092 us; speedup vs baseline: 1.4497x; 1.4497x over previous
//
#include <hip/hip_runtime.h>
#include <cstdint>
#include <cmath>

#define BB 256
#define DD 128
#define RR 2304
#define QQ 65536
#define WW (BB + QQ)                    // 65792
#define SCORE_SZ ((size_t)BB * WW)      // 16842752
#define TOPK 5
#define KSTEPS (RR / 32)                // 72

typedef __bf16 bf16x8 __attribute__((ext_vector_type(8)));
typedef float f32x4 __attribute__((ext_vector_type(4)));

__device__ inline ushort f32_to_bf16_rn(float f) {
  uint32_t u = __builtin_bit_cast(uint32_t, f);
  uint32_t r = (u + 0x7fffu + ((u >> 16) & 1u)) >> 16;
  return (ushort)r;
}
__device__ inline float bf16_to_f32(ushort h) {
  uint32_t u = ((uint32_t)h) << 16;
  return __builtin_bit_cast(float, u);
}

// A-scratch unit u = ((kc*16 + rt)*2 + h): 1024 B, lane L holds 16 B at L*16.
// Stored in score region: dword base = (u>>8)*WW + BB + (u&255)*256  (rows 0..8, cols>=256)
__device__ inline float* as_addr(float* out, int u, int L) {
  return out + (size_t)(u >> 8) * WW + BB + (size_t)((u & 255) * 256 + L * 4);
}

// ---------- Kernel A: row-normalize q and k ----------
__global__ __launch_bounds__(64) void norm_rows_kernel(
    const float* __restrict__ q, const float* __restrict__ k,
    float* __restrict__ qn, float* __restrict__ kn) {
  int b = blockIdx.x;
  const float* src;
  float* dst;
  if (b < BB) { src = q + (size_t)b * DD; dst = qn + (size_t)b * DD; }
  else        { src = k + (size_t)(b - BB) * DD; dst = kn + (size_t)(b - BB) * DD; }
  int t = threadIdx.x;
  float x0 = src[t], x1 = src[t + 64];
  float s = x0 * x0 + x1 * x1;
  #pragma unroll
  for (int o = 32; o > 0; o >>= 1) s += __shfl_down(s, o);
  s = __shfl(s, 0);
  float rn = 1.0f / sqrtf(s);
  dst[t] = x0 * rn;
  dst[t + 64] = x1 * rn;
}

// ---------- Kernel A2: preconvert ref_feats to bf16 hi/lo in MFMA frag order ----------
__global__ __launch_bounds__(64) void conv_a_kernel(
    const float* __restrict__ A, float* out) {
  int blk = blockIdx.x;           // 0..1151 = kc*16 + rt
  int L = threadIdx.x;            // 0..63
  int rt = blk & 15;
  int kc = blk >> 4;
  int m = rt * 16 + (L & 15);
  int k = kc * 32 + (L >> 4) * 8;
  const float* src = A + (size_t)m * RR + k;
  float4 v0 = *(const float4*)(src);
  float4 v1 = *(const float4*)(src + 4);
  float f[8] = {v0.x, v0.y, v0.z, v0.w, v1.x, v1.y, v1.z, v1.w};
  ushort hi[8], lo[8];
  #pragma unroll
  for (int i = 0; i < 8; i++) {
    hi[i] = f32_to_bf16_rn(f[i]);
    lo[i] = f32_to_bf16_rn(f[i] - bf16_to_f32(hi[i]));
  }
  int u0 = blk * 2;
  *(float4*)as_addr(out, u0, L)     = *(float4*)hi;
  *(float4*)as_addr(out, u0 + 1, L) = *(float4*)lo;
}

// ---------- Kernel B: score_batch = qn @ kn^T, mask_batch ----------
__global__ __launch_bounds__(256) void batch_kernel(
    const float* __restrict__ qn, const float* __restrict__ kn,
    const int* __restrict__ indices, float* __restrict__ out) {
  int i = blockIdx.x;
  int j = threadIdx.x;
  __shared__ float qs[DD];
  if (j < DD) qs[j] = qn[(size_t)i * DD + j];
  __syncthreads();
  const float* kr = kn + (size_t)j * DD;
  float acc = 0.f;
  #pragma unroll 8
  for (int d = 0; d < DD; d++) acc = fmaf(qs[d], kr[d], acc);
  out[(size_t)i * WW + j] = acc;
  out[SCORE_SZ + (size_t)i * WW + j] = (indices[i] == indices[j]) ? 1.0f : 0.0f;
}

// ---------- Kernel C1: score_ref = ref_feats @ ref_queue via split-bf16 MFMA ----------
// Grid: 1024 blocks (BN=64), 256 threads = 4 waves; wave w computes rows [64w,64w+64).
// Writes raw score_ref into the MASK region of out (scratch; overwritten later).
__global__ __launch_bounds__(256) void gemm_ref_kernel(
    const float* __restrict__ Bm, float* out) {
  __shared__ ushort bHi[64][40];   // [n][k], 80 B row stride: 16B-aligned b128 reads
  __shared__ ushort bLo[64][40];
  int tid = threadIdx.x;
  int w = tid >> 6;
  int L = tid & 63;
  int lm = L & 15;
  int q4 = L >> 4;
  int nb = blockIdx.x * 64;

  f32x4 acc[4][4];
  #pragma unroll
  for (int i = 0; i < 4; i++)
    #pragma unroll
    for (int j = 0; j < 4; j++) acc[i][j] = (f32x4){0.f, 0.f, 0.f, 0.f};

  // staging role: thread covers column nS, k-rows gS*8..gS*8+7
  int nS = tid & 63;
  int gS = tid >> 6;
  const float* bsrc = Bm + (size_t)(gS * 8) * QQ + nb + nS;

  for (int kc = 0; kc < KSTEPS; kc++) {
    // global loads for this k-chunk (no LDS dependency yet)
    float f[8];
    #pragma unroll
    for (int j = 0; j < 8; j++) f[j] = bsrc[(size_t)j * QQ];
    bsrc += (size_t)32 * QQ;

    __syncthreads();  // previous iteration's LDS reads complete
    ushort h[8], lo8[8];
    #pragma unroll
    for (int j = 0; j < 8; j++) {
      h[j] = f32_to_bf16_rn(f[j]);
      lo8[j] = f32_to_bf16_rn(f[j] - bf16_to_f32(h[j]));
    }
    *(ushort4*)&bHi[nS][gS * 8]     = ushort4{h[0], h[1], h[2], h[3]};
    *(ushort4*)&bHi[nS][gS * 8 + 4] = ushort4{h[4], h[5], h[6], h[7]};
    *(ushort4*)&bLo[nS][gS * 8]     = ushort4{lo8[0], lo8[1], lo8[2], lo8[3]};
    *(ushort4*)&bLo[nS][gS * 8 + 4] = ushort4{lo8[4], lo8[5], lo8[6], lo8[7]};
    __syncthreads();

    // A fragments: direct from L2-resident preconverted scratch, frag-ordered
    bf16x8 ah[4], al[4];
    #pragma unroll
    for (int rt = 0; rt < 4; rt++) {
      int u = (kc * 16 + w * 4 + rt) * 2;
      ah[rt] = __builtin_bit_cast(bf16x8, *(const float4*)as_addr(out, u, L));
      al[rt] = __builtin_bit_cast(bf16x8, *(const float4*)as_addr(out, u + 1, L));
    }
    #pragma unroll
    for (int ct = 0; ct < 4; ct++) {
      bf16x8 bh = __builtin_bit_cast(bf16x8, *(const float4*)&bHi[ct * 16 + lm][q4 * 8]);
      bf16x8 bl = __builtin_bit_cast(bf16x8, *(const float4*)&bLo[ct * 16 + lm][q4 * 8]);
      #pragma unroll
      for (int rt = 0; rt < 4; rt++) {
        acc[rt][ct] = __builtin_amdgcn_mfma_f32_16x16x32_bf16(al[rt], bh, acc[rt][ct], 0, 0, 0);
        acc[rt][ct] = __builtin_amdgcn_mfma_f32_16x16x32_bf16(ah[rt], bl, acc[rt][ct], 0, 0, 0);
        acc[rt][ct] = __builtin_amdgcn_mfma_f32_16x16x32_bf16(ah[rt], bh, acc[rt][ct], 0, 0, 0);
      }
    }
  }

  // epilogue: C/D layout col=lane&15, row=quad*4+reg
  float* dst = out + SCORE_SZ;
  #pragma unroll
  for (int rt = 0; rt < 4; rt++) {
    #pragma unroll
    for (int ct = 0; ct < 4; ct++) {
      int col = nb + ct * 16 + lm;
      #pragma unroll
      for (int r = 0; r < 4; r++) {
        int row = w * 64 + rt * 16 + q4 * 4 + r;
        dst[(size_t)row * WW + BB + col] = acc[rt][ct][r];
      }
    }
  }
}

// ---------- Kernel C2: score_queue = qn @ moco; write -score_queue*score_ref ----------
__global__ __launch_bounds__(256) void gemm_moco_kernel(
    const float* __restrict__ A,   // qn [256, 128]
    const float* __restrict__ Bm,  // moco [128, 65536]
    float* __restrict__ out) {
  __shared__ __align__(16) float aT[16][256];
  __shared__ __align__(16) float bT[16][64];
  int tid = threadIdx.x;
  int tx = tid & 7;
  int ty = tid >> 3;
  int cbase = blockIdx.x * 64;
  float acc[8][8] = {};

  for (int r0 = 0; r0 < DD; r0 += 16) {
    __syncthreads();
    {
      const float4* src4 = (const float4*)(A + (size_t)tid * DD + r0);
      #pragma unroll
      for (int g = 0; g < 4; g++) {
        float4 v = src4[g];
        aT[4 * g + 0][tid] = v.x;
        aT[4 * g + 1][tid] = v.y;
        aT[4 * g + 2][tid] = v.z;
        aT[4 * g + 3][tid] = v.w;
      }
    }
    {
      int col = tid & 63, kk = tid >> 6;
      #pragma unroll
      for (int i = 0; i < 4; i++)
        bT[kk + 4 * i][col] = Bm[(size_t)(r0 + kk + 4 * i) * QQ + cbase + col];
    }
    __syncthreads();
    #pragma unroll 4
    for (int kk = 0; kk < 16; kk++) {
      float av[8], bv[8];
      *(float4*)(&av[0]) = *(const float4*)(&aT[kk][ty * 8]);
      *(float4*)(&av[4]) = *(const float4*)(&aT[kk][ty * 8 + 4]);
      *(float4*)(&bv[0]) = *(const float4*)(&bT[kk][tx * 8]);
      *(float4*)(&bv[4]) = *(const float4*)(&bT[kk][tx * 8 + 4]);
      #pragma unroll
      for (int i = 0; i < 8; i++)
        #pragma unroll
        for (int j = 0; j < 8; j++)
          acc[i][j] = fmaf(av[i], bv[j], acc[i][j]);
    }
  }
  const float* sref = out + SCORE_SZ;  // raw score_ref from C1
  #pragma unroll
  for (int i = 0; i < 8; i++) {
    int row = ty * 8 + i;
    size_t off = (size_t)row * WW + BB + cbase + tx * 8;
    float4 s0 = *(const float4*)(sref + off);
    float4 s1 = *(const float4*)(sref + off + 4);
    float4 w0 = {-acc[i][0] * s0.x, -acc[i][1] * s0.y, -acc[i][2] * s0.z, -acc[i][3] * s0.w};
    float4 w1 = {-acc[i][4] * s1.x, -acc[i][5] * s1.y, -acc[i][6] * s1.z, -acc[i][7] * s1.w};
    *(float4*)(out + off) = w0;
    *(float4*)(out + off + 4) = w1;
  }
}

// ---------- Kernel T: per-row top-5 of masked score_ref ----------
__global__ __launch_bounds__(256) void topk_kernel(
    const float* __restrict__ out, const int* __restrict__ indices,
    const int* __restrict__ index_queue, int* __restrict__ topk_out) {
  int row = blockIdx.x;
  int t = threadIdx.x;
  int myi = indices[row];
  const float* s = out + SCORE_SZ + (size_t)row * WW + BB;
  float tv[TOPK];
  int ti[TOPK];
  #pragma unroll
  for (int i = 0; i < TOPK; i++) { tv[i] = -INFINITY; ti[i] = 0x7fffffff; }
  for (int it = 0; it < QQ / 256; it++) {
    int j = (it << 8) + t;  // ascending per thread -> ties keep smaller j
    float val = (index_queue[j] == myi) ? -INFINITY : s[j];
    if (val > tv[TOPK - 1]) {
      tv[TOPK - 1] = val; ti[TOPK - 1] = j;
      #pragma unroll
      for (int u = TOPK - 2; u >= 0; u--) {
        if (tv[u + 1] > tv[u]) {
          float fv = tv[u]; tv[u] = tv[u + 1]; tv[u + 1] = fv;
          int fi = ti[u]; ti[u] = ti[u + 1]; ti[u + 1] = fi;
        }
      }
    }
  }
  __shared__ float cv[256 * TOPK];
  __shared__ int ci[256 * TOPK];
  #pragma unroll
  for (int i = 0; i < TOPK; i++) { cv[t * TOPK + i] = tv[i]; ci[t * TOPK + i] = ti[i]; }
  __syncthreads();
  if (t == 0) {
    float bv[TOPK];
    int bi[TOPK];
    #pragma unroll
    for (int i = 0; i < TOPK; i++) { bv[i] = -INFINITY; bi[i] = 0x7fffffff; }
    for (int c = 0; c < 256 * TOPK; c++) {
      float val = cv[c]; int idx = ci[c];
      if (val > bv[TOPK - 1] || (val == bv[TOPK - 1] && idx < bi[TOPK - 1])) {
        bv[TOPK - 1] = val; bi[TOPK - 1] = idx;
        #pragma unroll
        for (int u = TOPK - 2; u >= 0; u--) {
          bool sw = (bv[u + 1] > bv[u]) || (bv[u + 1] == bv[u] && bi[u + 1] < bi[u]);
          if (sw) {
            float fv = bv[u]; bv[u] = bv[u + 1]; bv[u + 1] = fv;
            int fi = bi[u]; bi[u] = bi[u + 1]; bi[u + 1] = fi;
          }
        }
      }
    }
    #pragma unroll
    for (int i = 0; i < TOPK; i++) topk_out[row * TOPK + i] = bi[i];
  }
}

// ---------- Kernel M: overwrite mask region with base index-match mask ----------
__global__ __launch_bounds__(256) void mask_fill_kernel(
    const int* __restrict__ indices, const int* __restrict__ index_queue,
    float* __restrict__ out) {
  int row = blockIdx.x >> 8;
  int j = ((blockIdx.x & 255) << 8) + threadIdx.x;
  out[SCORE_SZ + (size_t)row * WW + BB + j] =
      (indices[row] == index_queue[j]) ? 1.0f : 0.0f;
}

// ---------- Kernel F: topk fixups (weighted_mask=+1, mask=1) ----------
__global__ __launch_bounds__(64) void fixup_kernel(
    const int* __restrict__ topk_idx, float* __restrict__ out) {
  int t = blockIdx.x * 64 + threadIdx.x;
  if (t >= BB * TOPK) return;
  int row = t / TOPK;
  int j = topk_idx[t];
  size_t o = (size_t)row * WW + BB + j;
  out[o] = -out[o];            // flip weighted_mask -1 -> +1
  out[SCORE_SZ + o] = 1.0f;    // mask set(1)
}

extern "C" void kernel_launch(void* const* d_in, const int* in_sizes, int n_in,
                              void* d_out, int out_size, void* d_ws, size_t ws_size,
                              hipStream_t stream) {
  (void)in_sizes; (void)n_in; (void)out_size; (void)ws_size;
  const float* q = (const float*)d_in[0];
  const float* k = (const float*)d_in[1];
  const float* ref_feats = (const float*)d_in[2];
  const float* moco_queue = (const float*)d_in[3];
  const float* ref_queue = (const float*)d_in[4];
  const int* indices = (const int*)d_in[5];
  const int* index_queue = (const int*)d_in[6];
  float* out = (float*)d_out;

  float* qn = (float*)d_ws;
  float* kn = qn + BB * DD;
  int* topk_idx = (int*)(kn + BB * DD);

  hipLaunchKernelGGL(norm_rows_kernel, dim3(2 * BB), dim3(64), 0, stream, q, k, qn, kn);
  hipLaunchKernelGGL(conv_a_kernel, dim3(KSTEPS * 16), dim3(64), 0, stream, ref_feats, out);
  hipLaunchKernelGGL(batch_kernel, dim3(BB), dim3(256), 0, stream, qn, kn, indices, out);
  hipLaunchKernelGGL(gemm_ref_kernel, dim3(QQ / 64), dim3(256), 0, stream, ref_queue, out);
  hipLaunchKernelGGL(gemm_moco_kernel, dim3(QQ / 64), dim3(256), 0, stream, qn, moco_queue, out);
  hipLaunchKernelGGL(topk_kernel, dim3(BB), dim3(256), 0, stream, out, indices, index_queue, topk_idx);
  hipLaunchKernelGGL(mask_fill_kernel, dim3(BB * 256), dim3(256), 0, stream, indices, index_queue, out);
  hipLaunchKernelGGL(fixup_kernel, dim3(20), dim3(64), 0, stream, topk_idx, out);
}